// Round 6
// baseline (91.162 us; speedup 1.0000x reference)
//
#include <hip/hip_runtime.h>
#include <math.h>

// ---- problem constants ----
#define DG   32
#define UF   4
#define ZB   16
#define FD   16
#define HH   128
#define WWID 128
#define SNUM 128
#define BATCH 2
#define RAYS  8192
#define NTOK  2048
#define DINP  512
#define ODIM  4096
#define MLPH  32

// d_out float offsets: (pred_depths, weights, nfg)
#define OUT_PRED_OFF 0
#define OUT_W_OFF    (BATCH*RAYS)
#define OUT_NFG_OFF  (OUT_W_OFF + BATCH*RAYS*SNUM)

typedef _Float16 half8 __attribute__((ext_vector_type(8)));
typedef _Float16 half4 __attribute__((ext_vector_type(4)));
typedef _Float16 h2 __attribute__((ext_vector_type(2)));
typedef float f32x4 __attribute__((ext_vector_type(4)));

#define GLDS16(gp, lp) \
    __builtin_amdgcn_global_load_lds((const __attribute__((address_space(1))) void*)(gp), \
                                     (__attribute__((address_space(3))) void*)(lp), 16, 0, 0)

// ---------------- merged prep: blocks [0,NTOK) = LayerNorm, [NTOK,NTOK+512) = W1 transpose ----------------
__global__ __launch_bounds__(256) void prep_kernel(const float* __restrict__ dec,
                                                   const float* __restrict__ lng,
                                                   const float* __restrict__ lnb,
                                                   const float* __restrict__ W2,
                                                   const float* __restrict__ b2,
                                                   const float* __restrict__ W3,
                                                   const float* __restrict__ W1,
                                                   _Float16* __restrict__ Af,
                                                   _Float16* __restrict__ W1T,
                                                   _Float16* __restrict__ W2f,
                                                   float* __restrict__ b2f,
                                                   float* __restrict__ w3f) {
    int tid = threadIdx.x;
    if (blockIdx.x < NTOK) {
        // ---- LayerNorm -> f16 A (block 0 also packs MLP frags) ----
        int t = blockIdx.x;
        const float2* row = reinterpret_cast<const float2*>(dec + (size_t)t * DINP);
        float2 v = row[tid];

        __shared__ float red[4];
        __shared__ float stat[2];

        float s = v.x + v.y;
        #pragma unroll
        for (int o = 32; o > 0; o >>= 1) s += __shfl_down(s, o);
        if ((tid & 63) == 0) red[tid >> 6] = s;
        __syncthreads();
        if (tid == 0) stat[0] = (red[0] + red[1] + red[2] + red[3]) * (1.0f / DINP);
        __syncthreads();
        float mu = stat[0];

        float dx = v.x - mu, dy = v.y - mu;
        float q = dx * dx + dy * dy;
        #pragma unroll
        for (int o = 32; o > 0; o >>= 1) q += __shfl_down(q, o);
        if ((tid & 63) == 0) red[tid >> 6] = q;
        __syncthreads();
        if (tid == 0) {
            float var = (red[0] + red[1] + red[2] + red[3]) * (1.0f / DINP);
            stat[1] = 1.0f / sqrtf(var + 1e-5f);
        }
        __syncthreads();
        float rstd = stat[1];

        int c = 2 * tid;
        h2 o2;
        o2.x = (_Float16)(dx * rstd * lng[c]     + lnb[c]);
        o2.y = (_Float16)(dy * rstd * lng[c + 1] + lnb[c + 1]);
        *reinterpret_cast<h2*>(Af + (size_t)t * DINP + c) = o2;

        // block 0: pack MLP weights into MFMA fragment order.
        if (blockIdx.x == 0 && tid < 128) {
            int jt = tid >> 6, l = tid & 63;
            int sub = l & 15, g = l >> 4;
            #pragma unroll
            for (int e = 0; e < 4; ++e) {
                W2f[(jt * 64 + l) * 4 + e] = (_Float16)W2[(g * 4 + e) * MLPH + jt * 16 + sub];
                b2f[(jt * 64 + l) * 4 + e] = b2[jt * 16 + g * 4 + e];
                w3f[(jt * 64 + l) * 4 + e] = W3[jt * 16 + g * 4 + e];
            }
        }
    } else {
        // ---- W1 (512x4096 f32) -> W1T (4096x512 f16) ----
        __shared__ float st[64][65];
        int blk = blockIdx.x - NTOK;          // [0, 512)
        int c0 = (blk & 63) * 64;
        int k0 = (blk >> 6) * 64;
        {
            int r = tid >> 2, cq = (tid & 3) * 16;
            const float* src = W1 + (size_t)(k0 + r) * ODIM + c0 + cq;
            #pragma unroll
            for (int qq = 0; qq < 4; ++qq) {
                float4 v = *reinterpret_cast<const float4*>(src + qq * 4);
                st[r][cq + qq * 4 + 0] = v.x;
                st[r][cq + qq * 4 + 1] = v.y;
                st[r][cq + qq * 4 + 2] = v.z;
                st[r][cq + qq * 4 + 3] = v.w;
            }
        }
        __syncthreads();
        {
            int cc = tid >> 2, kq = (tid & 3) * 16;
            _Float16 tmp[16];
            #pragma unroll
            for (int i = 0; i < 16; ++i) tmp[i] = (_Float16)st[kq + i][cc];
            _Float16* dst = W1T + (size_t)(c0 + cc) * DINP + k0 + kq;
            *reinterpret_cast<half8*>(dst)     = *reinterpret_cast<half8*>(&tmp[0]);
            *reinterpret_cast<half8*>(dst + 8) = *reinterpret_cast<half8*>(&tmp[8]);
        }
    }
}

// ---------------- MFMA GEMM -> grid_h (B,Z,H,W,F) f16 AND nfg (B,F,Z,H,W) f32 ----------------
// tp_kernel fused into the epilogue: nfg value = (float) of the SAME f16 the gh
// store produces -> bit-identical to the old separate transpose pass, but saves
// the 16.8 MB gh re-read and a full dependent dispatch; the 33.5 MB nfg write
// streams out under the other waves' K-loops.
__global__ __launch_bounds__(256, 2) void gemm_mfma_kernel(
        const _Float16* __restrict__ Af, const _Float16* __restrict__ W1T,
        const float* __restrict__ bias, _Float16* __restrict__ gh,
        float* __restrict__ nfg) {
    __shared__ _Float16 As[128 * 32];
    __shared__ _Float16 Bs[128 * 32];

    int tid = threadIdx.x;
    int l = tid & 63, w = tid >> 6;
    int wr = w >> 1, wc = w & 1;
    int row0 = blockIdx.y * 128;
    int col0 = blockIdx.x * 128;

    const char* Ag0 = (const char*)Af + (size_t)(row0 + w * 32 + (l >> 2)) * (DINP * 2) + (l & 3) * 16;
    const char* Ag1 = Ag0 + 16 * (DINP * 2);
    const char* Bg0 = (const char*)W1T + (size_t)(col0 + w * 32 + (l >> 2)) * (DINP * 2) + (l & 3) * 16;
    const char* Bg1 = Bg0 + 16 * (DINP * 2);
    char* lA0 = (char*)As + w * 2048;
    char* lA1 = lA0 + 1024;
    char* lB0 = (char*)Bs + w * 2048;
    char* lB1 = lB0 + 1024;

    f32x4 acc[4][4] = {};

    for (int kk = 0; kk < DINP; kk += 32) {
        GLDS16(Ag0, lA0); GLDS16(Ag1, lA1);
        GLDS16(Bg0, lB0); GLDS16(Bg1, lB1);
        Ag0 += 64; Ag1 += 64; Bg0 += 64; Bg1 += 64;
        __syncthreads();

        half8 af[4], bf[4];
        #pragma unroll
        for (int m = 0; m < 4; ++m)
            af[m] = *reinterpret_cast<const half8*>(As + (wr * 64 + m * 16 + (l & 15)) * 32 + (l >> 4) * 8);
        #pragma unroll
        for (int n = 0; n < 4; ++n)
            bf[n] = *reinterpret_cast<const half8*>(Bs + (wc * 64 + n * 16 + (l & 15)) * 32 + (l >> 4) * 8);
        #pragma unroll
        for (int m = 0; m < 4; ++m)
            #pragma unroll
            for (int n = 0; n < 4; ++n)
                acc[m][n] = __builtin_amdgcn_mfma_f32_16x16x32_f16(af[m], bf[n], acc[m][n], 0, 0, 0);
        __syncthreads();
    }

    #pragma unroll
    for (int n = 0; n < 4; ++n) {
        int c = col0 + wc * 64 + n * 16 + (l & 15);
        float bv = bias[c];
        int f = c & 15, z = (c >> 4) & 15, v = (c >> 8) & 3, u = (c >> 10) & 3;
        #pragma unroll
        for (int m = 0; m < 4; ++m) {
            int rbase = row0 + wr * 64 + m * 16 + ((l >> 4) << 2);
            #pragma unroll
            for (int j = 0; j < 4; ++j) {
                int t = rbase + j;
                int bb = t >> 10;
                int g = t & 1023;
                int i = g >> 5, j2 = g & 31;
                int h = i * 4 + u, wq = j2 * 4 + v;
                _Float16 hv = (_Float16)(acc[m][n][j] + bv);
                size_t gaddr = ((((size_t)(bb * ZB + z) * HH + h) * WWID + wq) << 4) + f;
                gh[gaddr] = hv;
                size_t naddr = (((size_t)(bb * FD + f) * ZB + z) * HH + h) * WWID + wq;
                nfg[naddr] = (float)hv;
            }
        }
    }
}

// ---------------- gather helper: trilinear via 4x 64B pair-loads (w-corners contiguous) ----------------
// (round-2 proven version, bit-identical accumulation)
__device__ __forceinline__ void gather_feat(const _Float16* __restrict__ gb,
                                            float px, float py, float pz,
                                            h2* __restrict__ a) {
    float fw = (py * (1.0f / 51.2f) + 1.0f) * 63.5f;
    float fh = (px * (1.0f / 51.2f) + 1.0f) * 63.5f;
    float fd = (pz + 5.0f) * (0.25f * 7.5f);
    float w0f = floorf(fw), h0f = floorf(fh), d0f = floorf(fd);
    float tw = fw - w0f, th = fh - h0f, td = fd - d0f;
    int w0 = (int)w0f, h0 = (int)h0f, d0 = (int)d0f;

    float aw0 = (w0 >= 0 && w0 <= WWID - 1) ? (1.0f - tw) : 0.0f;
    float aw1 = (w0 + 1 >= 0 && w0 + 1 <= WWID - 1) ? tw : 0.0f;
    float ah0 = (h0 >= 0 && h0 <= HH - 1) ? (1.0f - th) : 0.0f;
    float ah1 = (h0 + 1 >= 0 && h0 + 1 <= HH - 1) ? th : 0.0f;
    float ad0 = (d0 >= 0 && d0 <= ZB - 1) ? (1.0f - td) : 0.0f;
    float ad1 = (d0 + 1 >= 0 && d0 + 1 <= ZB - 1) ? td : 0.0f;

    // all-corner-weights-zero -> output is exactly zero; skip every load.
    if ((ad0 + ad1) * (ah0 + ah1) * (aw0 + aw1) <= 0.0f) return;

    int h0c = min(max(h0, 0), HH - 1),   h1c = min(max(h0 + 1, 0), HH - 1);
    int d0c = min(max(d0, 0), ZB - 1),   d1c = min(max(d0 + 1, 0), ZB - 1);
    // w pair: both slots always valid memory; weights route aw0/aw1 to the right slot.
    int wb = min(max(w0, 0), WWID - 2);
    float ws0 = (wb == w0) ? aw0 : ((wb == w0 + 1) ? aw1 : 0.0f);
    float ws1 = (wb == w0) ? aw1 : ((wb == w0 - 1) ? aw0 : 0.0f);

    int od0 = d0c * (HH * WWID * FD), od1 = d1c * (HH * WWID * FD);
    int oh0 = h0c * (WWID * FD),      oh1 = h1c * (WWID * FD);
    int ow  = wb * FD;

#define CPAIR(OFF, WDH) do { \
        const uint4* cp_ = reinterpret_cast<const uint4*>(gb + (OFF)); \
        uint4 A_ = cp_[0], B_ = cp_[1], C_ = cp_[2], D_ = cp_[3]; \
        _Float16 u0_ = (_Float16)((WDH) * ws0); \
        _Float16 u1_ = (_Float16)((WDH) * ws1); \
        h2 W0_ = {u0_, u0_}; h2 W1_ = {u1_, u1_}; \
        a[0] += __builtin_bit_cast(h2, A_.x) * W0_; \
        a[1] += __builtin_bit_cast(h2, A_.y) * W0_; \
        a[2] += __builtin_bit_cast(h2, A_.z) * W0_; \
        a[3] += __builtin_bit_cast(h2, A_.w) * W0_; \
        a[4] += __builtin_bit_cast(h2, B_.x) * W0_; \
        a[5] += __builtin_bit_cast(h2, B_.y) * W0_; \
        a[6] += __builtin_bit_cast(h2, B_.z) * W0_; \
        a[7] += __builtin_bit_cast(h2, B_.w) * W0_; \
        a[0] += __builtin_bit_cast(h2, C_.x) * W1_; \
        a[1] += __builtin_bit_cast(h2, C_.y) * W1_; \
        a[2] += __builtin_bit_cast(h2, C_.z) * W1_; \
        a[3] += __builtin_bit_cast(h2, C_.w) * W1_; \
        a[4] += __builtin_bit_cast(h2, D_.x) * W1_; \
        a[5] += __builtin_bit_cast(h2, D_.y) * W1_; \
        a[6] += __builtin_bit_cast(h2, D_.z) * W1_; \
        a[7] += __builtin_bit_cast(h2, D_.w) * W1_; \
    } while (0)

    CPAIR(od0 + oh0 + ow, ad0 * ah0);
    CPAIR(od0 + oh1 + ow, ad0 * ah1);
    CPAIR(od1 + oh0 + ow, ad1 * ah0);
    CPAIR(od1 + oh1 + ow, ad1 * ah1);
#undef CPAIR
}

// ---------------- fused ray kernel: ONE WAVE PER RAY (round-2 proven version) ----------------
// 12 KB/block, time-shared 64-row LDS buffer between the two sample sets.
#define SF 24   // feat LDS stride (halves): 48B rows -> 16B aligned, 2-way banks max
__global__ __launch_bounds__(256) void ray_fused_kernel(
        const float* __restrict__ orig, const float* __restrict__ dirs,
        const _Float16* __restrict__ gh,
        const _Float16* __restrict__ W2f, const float* __restrict__ b2f,
        const float* __restrict__ w3f, const float* __restrict__ b3,
        float* __restrict__ pred_out, float* __restrict__ w_out) {
    int tid = threadIdx.x;
    int lane = tid & 63, wvid = tid >> 6;
    int ray = blockIdx.x * 4 + wvid;
    int bb = ray >> 13;

    __shared__ _Float16 featLDS[4 * 64 * SF];   // 12KB
    _Float16* FL = &featLDS[wvid * 64 * SF];

    const float* o3 = orig + (size_t)ray * 3;
    const float* d3 = dirs + (size_t)ray * 3;
    float ox = o3[0], oy = o3[1], oz = o3[2];
    float dx = d3[0], dy = d3[1], dz = d3[2];

    const _Float16* gb = gh + (size_t)bb * (ZB * HH * WWID * FD);

    float t0 = 1.0f + 49.0f * ((float)lane * (1.0f / 127.0f));
    float t1 = 1.0f + 49.0f * ((float)(lane + 64) * (1.0f / 127.0f));

    h2 acc0[8] = {}, acc1[8] = {};
    gather_feat(gb, ox + dx * t0, oy + dy * t0, oz + dz * t0, acc0);
    gather_feat(gb, ox + dx * t1, oy + dy * t1, oz + dz * t1, acc1);

    half4 Af0 = *reinterpret_cast<const half4*>(W2f + lane * 4);
    half4 Af1 = *reinterpret_cast<const half4*>(W2f + (64 + lane) * 4);
    f32x4 b20 = *reinterpret_cast<const f32x4*>(b2f + lane * 4);
    f32x4 b21 = *reinterpret_cast<const f32x4*>(b2f + (64 + lane) * 4);
    f32x4 w30 = *reinterpret_cast<const f32x4*>(w3f + lane * 4);
    f32x4 w31 = *reinterpret_cast<const f32x4*>(w3f + (64 + lane) * 4);
    float b3v = b3[0];

    float at[8];

    // ---- pass A: samples 0..63 (acc0) ----
    {
        uint4 p0, p1;
        p0.x = __builtin_bit_cast(unsigned int, acc0[0]);
        p0.y = __builtin_bit_cast(unsigned int, acc0[1]);
        p0.z = __builtin_bit_cast(unsigned int, acc0[2]);
        p0.w = __builtin_bit_cast(unsigned int, acc0[3]);
        p1.x = __builtin_bit_cast(unsigned int, acc0[4]);
        p1.y = __builtin_bit_cast(unsigned int, acc0[5]);
        p1.z = __builtin_bit_cast(unsigned int, acc0[6]);
        p1.w = __builtin_bit_cast(unsigned int, acc0[7]);
        *reinterpret_cast<uint4*>(FL + lane * SF)     = p0;
        *reinterpret_cast<uint4*>(FL + lane * SF + 8) = p1;
        // same-wave ds_write -> ds_read: compiler inserts lgkmcnt wait; no barrier needed
        #pragma unroll
        for (int tt = 0; tt < 4; ++tt) {
            half4 bfrag = *reinterpret_cast<const half4*>(
                FL + (tt * 16 + (lane & 15)) * SF + (lane >> 4) * 4);
            f32x4 c0 = __builtin_amdgcn_mfma_f32_16x16x16f16(Af0, bfrag, b20, 0, 0, 0);
            f32x4 c1 = __builtin_amdgcn_mfma_f32_16x16x16f16(Af1, bfrag, b21, 0, 0, 0);
            float p = 0.0f;
            #pragma unroll
            for (int r = 0; r < 4; ++r) {
                p = fmaf(fmaxf(c0[r], 0.0f), w30[r], p);
                p = fmaf(fmaxf(c1[r], 0.0f), w31[r], p);
            }
            p += __shfl_xor(p, 16);
            p += __shfl_xor(p, 32);
            at[tt] = p;
        }
    }
    // ---- pass B: samples 64..127 (acc1), same LDS rows (WAR ordered within wave) ----
    {
        uint4 q0, q1;
        q0.x = __builtin_bit_cast(unsigned int, acc1[0]);
        q0.y = __builtin_bit_cast(unsigned int, acc1[1]);
        q0.z = __builtin_bit_cast(unsigned int, acc1[2]);
        q0.w = __builtin_bit_cast(unsigned int, acc1[3]);
        q1.x = __builtin_bit_cast(unsigned int, acc1[4]);
        q1.y = __builtin_bit_cast(unsigned int, acc1[5]);
        q1.z = __builtin_bit_cast(unsigned int, acc1[6]);
        q1.w = __builtin_bit_cast(unsigned int, acc1[7]);
        *reinterpret_cast<uint4*>(FL + lane * SF)     = q0;
        *reinterpret_cast<uint4*>(FL + lane * SF + 8) = q1;
        #pragma unroll
        for (int tt = 0; tt < 4; ++tt) {
            half4 bfrag = *reinterpret_cast<const half4*>(
                FL + (tt * 16 + (lane & 15)) * SF + (lane >> 4) * 4);
            f32x4 c0 = __builtin_amdgcn_mfma_f32_16x16x16f16(Af0, bfrag, b20, 0, 0, 0);
            f32x4 c1 = __builtin_amdgcn_mfma_f32_16x16x16f16(Af1, bfrag, b21, 0, 0, 0);
            float p = 0.0f;
            #pragma unroll
            for (int r = 0; r < 4; ++r) {
                p = fmaf(fmaxf(c0[r], 0.0f), w30[r], p);
                p = fmaf(fmaxf(c1[r], 0.0f), w31[r], p);
            }
            p += __shfl_xor(p, 16);
            p += __shfl_xor(p, 32);
            at[tt + 4] = p;
        }
    }

    int g2 = lane >> 4;
    float aS0 = at[0];
    aS0 = (g2 == 1) ? at[1] : aS0;
    aS0 = (g2 == 2) ? at[2] : aS0;
    aS0 = (g2 == 3) ? at[3] : aS0;
    float aS1 = at[4];
    aS1 = (g2 == 1) ? at[5] : aS1;
    aS1 = (g2 == 2) ? at[6] : aS1;
    aS1 = (g2 == 3) ? at[7] : aS1;
    aS0 += b3v; aS1 += b3v;

    float alpha0 = 1.0f / (1.0f + __expf(-aS0));
    float alpha1 = 1.0f / (1.0f + __expf(-aS1));
    float oma0 = 1.0f - alpha0 + 1e-10f;
    float oma1 = 1.0f - alpha1 + 1e-10f;

    // inclusive product scan over first 64 samples
    float P = oma0;
    #pragma unroll
    for (int off = 1; off < 64; off <<= 1) {
        float u = __shfl_up(P, off);
        if (lane >= off) P *= u;
    }
    float T64 = __shfl(P, 63);      // product of samples 0..63
    // inclusive product scan over second 64 samples
    float Q = oma1;
    #pragma unroll
    for (int off = 1; off < 64; off <<= 1) {
        float u = __shfl_up(Q, off);
        if (lane >= off) Q *= u;
    }
    float e0 = __shfl_up(P, 1);
    if (lane == 0) e0 = 1.0f;
    float e1 = __shfl_up(Q, 1);
    e1 = (lane == 0) ? T64 : e1 * T64;

    float w0 = alpha0 * e0;
    float w1 = alpha1 * e1;
    w_out[(size_t)ray * SNUM + lane] = w0;
    w_out[(size_t)ray * SNUM + 64 + lane] = w1;

    float pv = w0 * t0 + w1 * t1;
    #pragma unroll
    for (int o = 32; o > 0; o >>= 1) pv += __shfl_xor(pv, o);
    if (lane == 0) pred_out[ray] = pv;
}

extern "C" void kernel_launch(void* const* d_in, const int* in_sizes, int n_in,
                              void* d_out, int out_size, void* d_ws, size_t ws_size,
                              hipStream_t stream) {
    const float* dec = (const float*)d_in[0];
    const float* ro  = (const float*)d_in[1];
    const float* rd  = (const float*)d_in[2];
    const float* lng = (const float*)d_in[3];
    const float* lnb = (const float*)d_in[4];
    const float* W1  = (const float*)d_in[5];
    const float* b1  = (const float*)d_in[6];
    const float* W2  = (const float*)d_in[7];
    const float* b2  = (const float*)d_in[8];
    const float* W3  = (const float*)d_in[9];
    const float* b3  = (const float*)d_in[10];

    float* out = (float*)d_out;
    char*  wsb = (char*)d_ws;
    _Float16* Af  = (_Float16*)wsb;                      // 2 MB
    _Float16* W1T = (_Float16*)(wsb + (2u << 20));       // 4 MB
    _Float16* gh  = (_Float16*)(wsb + (6u << 20));       // 16.8 MB
    _Float16* W2f = (_Float16*)(wsb + (23u << 20));              // 1 KB
    float*    b2f = (float*)(wsb + (23u << 20) + 4096);          // 2 KB
    float*    w3f = (float*)(wsb + (23u << 20) + 8192);          // 2 KB

    // dispatch 1: LN (blocks 0..2047) + W1 transpose (blocks 2048..2559)
    prep_kernel<<<NTOK + (ODIM / 64) * (DINP / 64), 256, 0, stream>>>(
        dec, lng, lnb, W2, b2, W3, W1, Af, W1T, W2f, b2f, w3f);

    // dispatch 2: GEMM with fused nfg-transpose epilogue (tp kernel eliminated)
    dim3 gg(ODIM / 128, NTOK / 128);
    gemm_mfma_kernel<<<gg, 256, 0, stream>>>(Af, W1T, b1, gh, out + OUT_NFG_OFF);

    // dispatch 3: ray march (round-2 proven structure)
    ray_fused_kernel<<<BATCH * RAYS / 4, 256, 0, stream>>>(ro, rd, gh, W2f, b2f, w3f, b3,
                                                           out + OUT_PRED_OFF, out + OUT_W_OFF);
}

// Round 7
// 64.475 us; speedup vs baseline: 1.4139x; 1.4139x over previous
//
#include <hip/hip_runtime.h>
#include <math.h>

// ---- problem constants ----
#define DG   32
#define UF   4
#define ZB   16
#define FD   16
#define HH   128
#define WWID 128
#define SNUM 128
#define BATCH 2
#define RAYS  8192
#define NTOK  2048
#define DINP  512
#define ODIM  4096
#define MLPH  32

// d_out float offsets: (pred_depths, weights, nfg)
#define OUT_PRED_OFF 0
#define OUT_W_OFF    (BATCH*RAYS)
#define OUT_NFG_OFF  (OUT_W_OFF + BATCH*RAYS*SNUM)

typedef _Float16 half8 __attribute__((ext_vector_type(8)));
typedef _Float16 half4 __attribute__((ext_vector_type(4)));
typedef _Float16 h2 __attribute__((ext_vector_type(2)));
typedef float f32x4 __attribute__((ext_vector_type(4)));

#define GLDS16(gp, lp) \
    __builtin_amdgcn_global_load_lds((const __attribute__((address_space(1))) void*)(gp), \
                                     (__attribute__((address_space(3))) void*)(lp), 16, 0, 0)

// ---------------- merged prep: blocks [0,NTOK) = LayerNorm, [NTOK,NTOK+512) = W1 transpose ----------------
__global__ __launch_bounds__(256) void prep_kernel(const float* __restrict__ dec,
                                                   const float* __restrict__ lng,
                                                   const float* __restrict__ lnb,
                                                   const float* __restrict__ W2,
                                                   const float* __restrict__ b2,
                                                   const float* __restrict__ W3,
                                                   const float* __restrict__ W1,
                                                   _Float16* __restrict__ Af,
                                                   _Float16* __restrict__ W1T,
                                                   _Float16* __restrict__ W2f,
                                                   float* __restrict__ b2f,
                                                   float* __restrict__ w3f) {
    int tid = threadIdx.x;
    if (blockIdx.x < NTOK) {
        // ---- LayerNorm -> f16 A (block 0 also packs MLP frags) ----
        int t = blockIdx.x;
        const float2* row = reinterpret_cast<const float2*>(dec + (size_t)t * DINP);
        float2 v = row[tid];

        __shared__ float red[4];
        __shared__ float stat[2];

        float s = v.x + v.y;
        #pragma unroll
        for (int o = 32; o > 0; o >>= 1) s += __shfl_down(s, o);
        if ((tid & 63) == 0) red[tid >> 6] = s;
        __syncthreads();
        if (tid == 0) stat[0] = (red[0] + red[1] + red[2] + red[3]) * (1.0f / DINP);
        __syncthreads();
        float mu = stat[0];

        float dx = v.x - mu, dy = v.y - mu;
        float q = dx * dx + dy * dy;
        #pragma unroll
        for (int o = 32; o > 0; o >>= 1) q += __shfl_down(q, o);
        if ((tid & 63) == 0) red[tid >> 6] = q;
        __syncthreads();
        if (tid == 0) {
            float var = (red[0] + red[1] + red[2] + red[3]) * (1.0f / DINP);
            stat[1] = 1.0f / sqrtf(var + 1e-5f);
        }
        __syncthreads();
        float rstd = stat[1];

        int c = 2 * tid;
        h2 o2;
        o2.x = (_Float16)(dx * rstd * lng[c]     + lnb[c]);
        o2.y = (_Float16)(dy * rstd * lng[c + 1] + lnb[c + 1]);
        *reinterpret_cast<h2*>(Af + (size_t)t * DINP + c) = o2;

        // block 0: pack MLP weights into MFMA fragment order.
        if (blockIdx.x == 0 && tid < 128) {
            int jt = tid >> 6, l = tid & 63;
            int sub = l & 15, g = l >> 4;
            #pragma unroll
            for (int e = 0; e < 4; ++e) {
                W2f[(jt * 64 + l) * 4 + e] = (_Float16)W2[(g * 4 + e) * MLPH + jt * 16 + sub];
                b2f[(jt * 64 + l) * 4 + e] = b2[jt * 16 + g * 4 + e];
                w3f[(jt * 64 + l) * 4 + e] = W3[jt * 16 + g * 4 + e];
            }
        }
    } else {
        // ---- W1 (512x4096 f32) -> W1T (4096x512 f16) ----
        __shared__ float st[64][65];
        int blk = blockIdx.x - NTOK;          // [0, 512)
        int c0 = (blk & 63) * 64;
        int k0 = (blk >> 6) * 64;
        {
            int r = tid >> 2, cq = (tid & 3) * 16;
            const float* src = W1 + (size_t)(k0 + r) * ODIM + c0 + cq;
            #pragma unroll
            for (int qq = 0; qq < 4; ++qq) {
                float4 v = *reinterpret_cast<const float4*>(src + qq * 4);
                st[r][cq + qq * 4 + 0] = v.x;
                st[r][cq + qq * 4 + 1] = v.y;
                st[r][cq + qq * 4 + 2] = v.z;
                st[r][cq + qq * 4 + 3] = v.w;
            }
        }
        __syncthreads();
        {
            int cc = tid >> 2, kq = (tid & 3) * 16;
            _Float16 tmp[16];
            #pragma unroll
            for (int i = 0; i < 16; ++i) tmp[i] = (_Float16)st[kq + i][cc];
            _Float16* dst = W1T + (size_t)(c0 + cc) * DINP + k0 + kq;
            *reinterpret_cast<half8*>(dst)     = *reinterpret_cast<half8*>(&tmp[0]);
            *reinterpret_cast<half8*>(dst + 8) = *reinterpret_cast<half8*>(&tmp[8]);
        }
    }
}

// ---------------- MFMA GEMM -> grid_h (B,Z,H,W,F) f16 ----------------
// 2-phase double-buffered K-loop (T3-minimum): issue next tile's global_load_lds
// BEFORE consuming the current tile; ONE __syncthreads per K-step (its vmcnt(0)
// drains a prefetch that flew over this step's ds_read+MFMA). Math/epilogue
// identical to the round-2 version -> bit-identical outputs.
__global__ __launch_bounds__(256, 2) void gemm_mfma_kernel(
        const _Float16* __restrict__ Af, const _Float16* __restrict__ W1T,
        const float* __restrict__ bias, _Float16* __restrict__ gh) {
    __shared__ _Float16 As[2][128 * 32];
    __shared__ _Float16 Bs[2][128 * 32];

    int tid = threadIdx.x;
    int l = tid & 63, w = tid >> 6;
    int wr = w >> 1, wc = w & 1;
    int row0 = blockIdx.y * 128;
    int col0 = blockIdx.x * 128;

    const char* Ag0 = (const char*)Af + (size_t)(row0 + w * 32 + (l >> 2)) * (DINP * 2) + (l & 3) * 16;
    const char* Ag1 = Ag0 + 16 * (DINP * 2);
    const char* Bg0 = (const char*)W1T + (size_t)(col0 + w * 32 + (l >> 2)) * (DINP * 2) + (l & 3) * 16;
    const char* Bg1 = Bg0 + 16 * (DINP * 2);

    f32x4 acc[4][4] = {};

    // prologue: stage K-step 0 into buffer 0
    {
        char* lA0 = (char*)As[0] + w * 2048;
        char* lB0 = (char*)Bs[0] + w * 2048;
        GLDS16(Ag0, lA0); GLDS16(Ag1, lA0 + 1024);
        GLDS16(Bg0, lB0); GLDS16(Bg1, lB0 + 1024);
        Ag0 += 64; Ag1 += 64; Bg0 += 64; Bg1 += 64;
    }
    __syncthreads();

    int cur = 0;
    for (int kk = 0; kk < DINP; kk += 32) {
        // issue next tile's staging first (flies over the ds_read+MFMA below)
        if (kk + 32 < DINP) {
            char* lA0 = (char*)As[cur ^ 1] + w * 2048;
            char* lB0 = (char*)Bs[cur ^ 1] + w * 2048;
            GLDS16(Ag0, lA0); GLDS16(Ag1, lA0 + 1024);
            GLDS16(Bg0, lB0); GLDS16(Bg1, lB0 + 1024);
            Ag0 += 64; Ag1 += 64; Bg0 += 64; Bg1 += 64;
        }

        half8 af[4], bf[4];
        #pragma unroll
        for (int m = 0; m < 4; ++m)
            af[m] = *reinterpret_cast<const half8*>(&As[cur][(wr * 64 + m * 16 + (l & 15)) * 32 + (l >> 4) * 8]);
        #pragma unroll
        for (int n = 0; n < 4; ++n)
            bf[n] = *reinterpret_cast<const half8*>(&Bs[cur][(wc * 64 + n * 16 + (l & 15)) * 32 + (l >> 4) * 8]);
        #pragma unroll
        for (int m = 0; m < 4; ++m)
            #pragma unroll
            for (int n = 0; n < 4; ++n)
                acc[m][n] = __builtin_amdgcn_mfma_f32_16x16x32_f16(af[m], bf[n], acc[m][n], 0, 0, 0);

        // one barrier per K-step: drains prefetch (vmcnt) + this step's ds_reads
        // (lgkmcnt) so next iteration may overwrite As[cur]/Bs[cur].
        __syncthreads();
        cur ^= 1;
    }

    #pragma unroll
    for (int n = 0; n < 4; ++n) {
        int c = col0 + wc * 64 + n * 16 + (l & 15);
        float bv = bias[c];
        int f = c & 15, z = (c >> 4) & 15, v = (c >> 8) & 3, u = (c >> 10) & 3;
        #pragma unroll
        for (int m = 0; m < 4; ++m) {
            int rbase = row0 + wr * 64 + m * 16 + ((l >> 4) << 2);
            #pragma unroll
            for (int j = 0; j < 4; ++j) {
                int t = rbase + j;
                int bb = t >> 10;
                int g = t & 1023;
                int i = g >> 5, j2 = g & 31;
                int h = i * 4 + u, wq = j2 * 4 + v;
                size_t gaddr = ((((size_t)(bb * ZB + z) * HH + h) * WWID + wq) << 4) + f;
                gh[gaddr] = (_Float16)(acc[m][n][j] + bv);
            }
        }
    }
}

// ---------------- transpose grid_h (B,Z,H,W,F) f16 -> nfg (B,F,Z,H,W) f32 ----------------
// (standalone again: its LDS transpose keeps the 33.5 MB f32 write coalesced;
// fusing into the gemm epilogue scattered the dwords -> 149 MB write traffic, round-6)
__global__ __launch_bounds__(256) void tp_kernel(const _Float16* __restrict__ gh,
                                                 float* __restrict__ nfg) {
    int blk = blockIdx.x;           // b*2048 + z*128 + h
    int bb = blk >> 11, z = (blk >> 7) & 15, h = blk & 127;
    __shared__ float sl[128 * 17];  // [w][f] padded
    int tid = threadIdx.x;
    const uint4* src = reinterpret_cast<const uint4*>(gh + (size_t)blk * 2048);
    uint4 v = src[tid];             // 8 f16; idx = tid*8
    int wv = tid >> 1, fb = (tid & 1) * 8;
    h2 p0 = __builtin_bit_cast(h2, v.x);
    h2 p1 = __builtin_bit_cast(h2, v.y);
    h2 p2 = __builtin_bit_cast(h2, v.z);
    h2 p3 = __builtin_bit_cast(h2, v.w);
    float* sr = &sl[wv * 17 + fb];
    sr[0] = (float)p0.x; sr[1] = (float)p0.y;
    sr[2] = (float)p1.x; sr[3] = (float)p1.y;
    sr[4] = (float)p2.x; sr[5] = (float)p2.y;
    sr[6] = (float)p3.x; sr[7] = (float)p3.y;
    __syncthreads();
    int f = tid >> 4, w0 = (tid & 15) * 8;
    float* dst = nfg + (((size_t)(bb * FD + f) * ZB + z) * (HH * WWID)) + h * WWID + w0;
    float4 o0, o1;
    o0.x = sl[(w0 + 0) * 17 + f]; o0.y = sl[(w0 + 1) * 17 + f];
    o0.z = sl[(w0 + 2) * 17 + f]; o0.w = sl[(w0 + 3) * 17 + f];
    o1.x = sl[(w0 + 4) * 17 + f]; o1.y = sl[(w0 + 5) * 17 + f];
    o1.z = sl[(w0 + 6) * 17 + f]; o1.w = sl[(w0 + 7) * 17 + f];
    *reinterpret_cast<float4*>(dst) = o0;
    *reinterpret_cast<float4*>(dst + 4) = o1;
}

// ---------------- gather helper: trilinear via 4x 64B pair-loads (w-corners contiguous) ----------------
// (round-2 proven version, bit-identical accumulation)
__device__ __forceinline__ void gather_feat(const _Float16* __restrict__ gb,
                                            float px, float py, float pz,
                                            h2* __restrict__ a) {
    float fw = (py * (1.0f / 51.2f) + 1.0f) * 63.5f;
    float fh = (px * (1.0f / 51.2f) + 1.0f) * 63.5f;
    float fd = (pz + 5.0f) * (0.25f * 7.5f);
    float w0f = floorf(fw), h0f = floorf(fh), d0f = floorf(fd);
    float tw = fw - w0f, th = fh - h0f, td = fd - d0f;
    int w0 = (int)w0f, h0 = (int)h0f, d0 = (int)d0f;

    float aw0 = (w0 >= 0 && w0 <= WWID - 1) ? (1.0f - tw) : 0.0f;
    float aw1 = (w0 + 1 >= 0 && w0 + 1 <= WWID - 1) ? tw : 0.0f;
    float ah0 = (h0 >= 0 && h0 <= HH - 1) ? (1.0f - th) : 0.0f;
    float ah1 = (h0 + 1 >= 0 && h0 + 1 <= HH - 1) ? th : 0.0f;
    float ad0 = (d0 >= 0 && d0 <= ZB - 1) ? (1.0f - td) : 0.0f;
    float ad1 = (d0 + 1 >= 0 && d0 + 1 <= ZB - 1) ? td : 0.0f;

    // all-corner-weights-zero -> output is exactly zero; skip every load.
    if ((ad0 + ad1) * (ah0 + ah1) * (aw0 + aw1) <= 0.0f) return;

    int h0c = min(max(h0, 0), HH - 1),   h1c = min(max(h0 + 1, 0), HH - 1);
    int d0c = min(max(d0, 0), ZB - 1),   d1c = min(max(d0 + 1, 0), ZB - 1);
    // w pair: both slots always valid memory; weights route aw0/aw1 to the right slot.
    int wb = min(max(w0, 0), WWID - 2);
    float ws0 = (wb == w0) ? aw0 : ((wb == w0 + 1) ? aw1 : 0.0f);
    float ws1 = (wb == w0) ? aw1 : ((wb == w0 - 1) ? aw0 : 0.0f);

    int od0 = d0c * (HH * WWID * FD), od1 = d1c * (HH * WWID * FD);
    int oh0 = h0c * (WWID * FD),      oh1 = h1c * (WWID * FD);
    int ow  = wb * FD;

#define CPAIR(OFF, WDH) do { \
        const uint4* cp_ = reinterpret_cast<const uint4*>(gb + (OFF)); \
        uint4 A_ = cp_[0], B_ = cp_[1], C_ = cp_[2], D_ = cp_[3]; \
        _Float16 u0_ = (_Float16)((WDH) * ws0); \
        _Float16 u1_ = (_Float16)((WDH) * ws1); \
        h2 W0_ = {u0_, u0_}; h2 W1_ = {u1_, u1_}; \
        a[0] += __builtin_bit_cast(h2, A_.x) * W0_; \
        a[1] += __builtin_bit_cast(h2, A_.y) * W0_; \
        a[2] += __builtin_bit_cast(h2, A_.z) * W0_; \
        a[3] += __builtin_bit_cast(h2, A_.w) * W0_; \
        a[4] += __builtin_bit_cast(h2, B_.x) * W0_; \
        a[5] += __builtin_bit_cast(h2, B_.y) * W0_; \
        a[6] += __builtin_bit_cast(h2, B_.z) * W0_; \
        a[7] += __builtin_bit_cast(h2, B_.w) * W0_; \
        a[0] += __builtin_bit_cast(h2, C_.x) * W1_; \
        a[1] += __builtin_bit_cast(h2, C_.y) * W1_; \
        a[2] += __builtin_bit_cast(h2, C_.z) * W1_; \
        a[3] += __builtin_bit_cast(h2, C_.w) * W1_; \
        a[4] += __builtin_bit_cast(h2, D_.x) * W1_; \
        a[5] += __builtin_bit_cast(h2, D_.y) * W1_; \
        a[6] += __builtin_bit_cast(h2, D_.z) * W1_; \
        a[7] += __builtin_bit_cast(h2, D_.w) * W1_; \
    } while (0)

    CPAIR(od0 + oh0 + ow, ad0 * ah0);
    CPAIR(od0 + oh1 + ow, ad0 * ah1);
    CPAIR(od1 + oh0 + ow, ad1 * ah0);
    CPAIR(od1 + oh1 + ow, ad1 * ah1);
#undef CPAIR
}

// ---------------- fused ray kernel: ONE WAVE PER RAY (round-2 proven version) ----------------
// 12 KB/block, time-shared 64-row LDS buffer between the two sample sets.
#define SF 24   // feat LDS stride (halves): 48B rows -> 16B aligned, 2-way banks max
__global__ __launch_bounds__(256) void ray_fused_kernel(
        const float* __restrict__ orig, const float* __restrict__ dirs,
        const _Float16* __restrict__ gh,
        const _Float16* __restrict__ W2f, const float* __restrict__ b2f,
        const float* __restrict__ w3f, const float* __restrict__ b3,
        float* __restrict__ pred_out, float* __restrict__ w_out) {
    int tid = threadIdx.x;
    int lane = tid & 63, wvid = tid >> 6;
    int ray = blockIdx.x * 4 + wvid;
    int bb = ray >> 13;

    __shared__ _Float16 featLDS[4 * 64 * SF];   // 12KB
    _Float16* FL = &featLDS[wvid * 64 * SF];

    const float* o3 = orig + (size_t)ray * 3;
    const float* d3 = dirs + (size_t)ray * 3;
    float ox = o3[0], oy = o3[1], oz = o3[2];
    float dx = d3[0], dy = d3[1], dz = d3[2];

    const _Float16* gb = gh + (size_t)bb * (ZB * HH * WWID * FD);

    float t0 = 1.0f + 49.0f * ((float)lane * (1.0f / 127.0f));
    float t1 = 1.0f + 49.0f * ((float)(lane + 64) * (1.0f / 127.0f));

    h2 acc0[8] = {}, acc1[8] = {};
    gather_feat(gb, ox + dx * t0, oy + dy * t0, oz + dz * t0, acc0);
    gather_feat(gb, ox + dx * t1, oy + dy * t1, oz + dz * t1, acc1);

    half4 Af0 = *reinterpret_cast<const half4*>(W2f + lane * 4);
    half4 Af1 = *reinterpret_cast<const half4*>(W2f + (64 + lane) * 4);
    f32x4 b20 = *reinterpret_cast<const f32x4*>(b2f + lane * 4);
    f32x4 b21 = *reinterpret_cast<const f32x4*>(b2f + (64 + lane) * 4);
    f32x4 w30 = *reinterpret_cast<const f32x4*>(w3f + lane * 4);
    f32x4 w31 = *reinterpret_cast<const f32x4*>(w3f + (64 + lane) * 4);
    float b3v = b3[0];

    float at[8];

    // ---- pass A: samples 0..63 (acc0) ----
    {
        uint4 p0, p1;
        p0.x = __builtin_bit_cast(unsigned int, acc0[0]);
        p0.y = __builtin_bit_cast(unsigned int, acc0[1]);
        p0.z = __builtin_bit_cast(unsigned int, acc0[2]);
        p0.w = __builtin_bit_cast(unsigned int, acc0[3]);
        p1.x = __builtin_bit_cast(unsigned int, acc0[4]);
        p1.y = __builtin_bit_cast(unsigned int, acc0[5]);
        p1.z = __builtin_bit_cast(unsigned int, acc0[6]);
        p1.w = __builtin_bit_cast(unsigned int, acc0[7]);
        *reinterpret_cast<uint4*>(FL + lane * SF)     = p0;
        *reinterpret_cast<uint4*>(FL + lane * SF + 8) = p1;
        // same-wave ds_write -> ds_read: compiler inserts lgkmcnt wait; no barrier needed
        #pragma unroll
        for (int tt = 0; tt < 4; ++tt) {
            half4 bfrag = *reinterpret_cast<const half4*>(
                FL + (tt * 16 + (lane & 15)) * SF + (lane >> 4) * 4);
            f32x4 c0 = __builtin_amdgcn_mfma_f32_16x16x16f16(Af0, bfrag, b20, 0, 0, 0);
            f32x4 c1 = __builtin_amdgcn_mfma_f32_16x16x16f16(Af1, bfrag, b21, 0, 0, 0);
            float p = 0.0f;
            #pragma unroll
            for (int r = 0; r < 4; ++r) {
                p = fmaf(fmaxf(c0[r], 0.0f), w30[r], p);
                p = fmaf(fmaxf(c1[r], 0.0f), w31[r], p);
            }
            p += __shfl_xor(p, 16);
            p += __shfl_xor(p, 32);
            at[tt] = p;
        }
    }
    // ---- pass B: samples 64..127 (acc1), same LDS rows (WAR ordered within wave) ----
    {
        uint4 q0, q1;
        q0.x = __builtin_bit_cast(unsigned int, acc1[0]);
        q0.y = __builtin_bit_cast(unsigned int, acc1[1]);
        q0.z = __builtin_bit_cast(unsigned int, acc1[2]);
        q0.w = __builtin_bit_cast(unsigned int, acc1[3]);
        q1.x = __builtin_bit_cast(unsigned int, acc1[4]);
        q1.y = __builtin_bit_cast(unsigned int, acc1[5]);
        q1.z = __builtin_bit_cast(unsigned int, acc1[6]);
        q1.w = __builtin_bit_cast(unsigned int, acc1[7]);
        *reinterpret_cast<uint4*>(FL + lane * SF)     = q0;
        *reinterpret_cast<uint4*>(FL + lane * SF + 8) = q1;
        #pragma unroll
        for (int tt = 0; tt < 4; ++tt) {
            half4 bfrag = *reinterpret_cast<const half4*>(
                FL + (tt * 16 + (lane & 15)) * SF + (lane >> 4) * 4);
            f32x4 c0 = __builtin_amdgcn_mfma_f32_16x16x16f16(Af0, bfrag, b20, 0, 0, 0);
            f32x4 c1 = __builtin_amdgcn_mfma_f32_16x16x16f16(Af1, bfrag, b21, 0, 0, 0);
            float p = 0.0f;
            #pragma unroll
            for (int r = 0; r < 4; ++r) {
                p = fmaf(fmaxf(c0[r], 0.0f), w30[r], p);
                p = fmaf(fmaxf(c1[r], 0.0f), w31[r], p);
            }
            p += __shfl_xor(p, 16);
            p += __shfl_xor(p, 32);
            at[tt + 4] = p;
        }
    }

    int g2 = lane >> 4;
    float aS0 = at[0];
    aS0 = (g2 == 1) ? at[1] : aS0;
    aS0 = (g2 == 2) ? at[2] : aS0;
    aS0 = (g2 == 3) ? at[3] : aS0;
    float aS1 = at[4];
    aS1 = (g2 == 1) ? at[5] : aS1;
    aS1 = (g2 == 2) ? at[6] : aS1;
    aS1 = (g2 == 3) ? at[7] : aS1;
    aS0 += b3v; aS1 += b3v;

    float alpha0 = 1.0f / (1.0f + __expf(-aS0));
    float alpha1 = 1.0f / (1.0f + __expf(-aS1));
    float oma0 = 1.0f - alpha0 + 1e-10f;
    float oma1 = 1.0f - alpha1 + 1e-10f;

    // inclusive product scan over first 64 samples
    float P = oma0;
    #pragma unroll
    for (int off = 1; off < 64; off <<= 1) {
        float u = __shfl_up(P, off);
        if (lane >= off) P *= u;
    }
    float T64 = __shfl(P, 63);      // product of samples 0..63
    // inclusive product scan over second 64 samples
    float Q = oma1;
    #pragma unroll
    for (int off = 1; off < 64; off <<= 1) {
        float u = __shfl_up(Q, off);
        if (lane >= off) Q *= u;
    }
    float e0 = __shfl_up(P, 1);
    if (lane == 0) e0 = 1.0f;
    float e1 = __shfl_up(Q, 1);
    e1 = (lane == 0) ? T64 : e1 * T64;

    float w0 = alpha0 * e0;
    float w1 = alpha1 * e1;
    w_out[(size_t)ray * SNUM + lane] = w0;
    w_out[(size_t)ray * SNUM + 64 + lane] = w1;

    float pv = w0 * t0 + w1 * t1;
    #pragma unroll
    for (int o = 32; o > 0; o >>= 1) pv += __shfl_xor(pv, o);
    if (lane == 0) pred_out[ray] = pv;
}

extern "C" void kernel_launch(void* const* d_in, const int* in_sizes, int n_in,
                              void* d_out, int out_size, void* d_ws, size_t ws_size,
                              hipStream_t stream) {
    const float* dec = (const float*)d_in[0];
    const float* ro  = (const float*)d_in[1];
    const float* rd  = (const float*)d_in[2];
    const float* lng = (const float*)d_in[3];
    const float* lnb = (const float*)d_in[4];
    const float* W1  = (const float*)d_in[5];
    const float* b1  = (const float*)d_in[6];
    const float* W2  = (const float*)d_in[7];
    const float* b2  = (const float*)d_in[8];
    const float* W3  = (const float*)d_in[9];
    const float* b3  = (const float*)d_in[10];

    float* out = (float*)d_out;
    char*  wsb = (char*)d_ws;
    _Float16* Af  = (_Float16*)wsb;                      // 2 MB
    _Float16* W1T = (_Float16*)(wsb + (2u << 20));       // 4 MB
    _Float16* gh  = (_Float16*)(wsb + (6u << 20));       // 16.8 MB
    _Float16* W2f = (_Float16*)(wsb + (23u << 20));              // 1 KB
    float*    b2f = (float*)(wsb + (23u << 20) + 4096);          // 2 KB
    float*    w3f = (float*)(wsb + (23u << 20) + 8192);          // 2 KB

    // dispatch 1: LN (blocks 0..2047) + W1 transpose (blocks 2048..2559)
    prep_kernel<<<NTOK + (ODIM / 64) * (DINP / 64), 256, 0, stream>>>(
        dec, lng, lnb, W2, b2, W3, W1, Af, W1T, W2f, b2f, w3f);

    // dispatch 2: GEMM (2-phase double-buffered K-loop)
    dim3 gg(ODIM / 128, NTOK / 128);
    gemm_mfma_kernel<<<gg, 256, 0, stream>>>(Af, W1T, b1, gh);

    // dispatch 3: ray march (round-2 proven structure)
    ray_fused_kernel<<<BATCH * RAYS / 4, 256, 0, stream>>>(ro, rd, gh, W2f, b2f, w3f, b3,
                                                           out + OUT_PRED_OFF, out + OUT_W_OFF);

    // dispatch 4: nfg transpose (standalone, coalesced writes)
    tp_kernel<<<BATCH * ZB * HH, 256, 0, stream>>>(gh, out + OUT_NFG_OFF);
}

// Round 8
// 62.237 us; speedup vs baseline: 1.4647x; 1.0360x over previous
//
#include <hip/hip_runtime.h>
#include <math.h>

// ---- problem constants ----
#define DG   32
#define UF   4
#define ZB   16
#define FD   16
#define HH   128
#define WWID 128
#define SNUM 128
#define BATCH 2
#define RAYS  8192
#define NTOK  2048
#define DINP  512
#define ODIM  4096
#define MLPH  32

// d_out float offsets: (pred_depths, weights, nfg)
#define OUT_PRED_OFF 0
#define OUT_W_OFF    (BATCH*RAYS)
#define OUT_NFG_OFF  (OUT_W_OFF + BATCH*RAYS*SNUM)

typedef _Float16 half8 __attribute__((ext_vector_type(8)));
typedef _Float16 half4 __attribute__((ext_vector_type(4)));
typedef _Float16 h2 __attribute__((ext_vector_type(2)));
typedef float f32x4 __attribute__((ext_vector_type(4)));

#define GLDS16(gp, lp) \
    __builtin_amdgcn_global_load_lds((const __attribute__((address_space(1))) void*)(gp), \
                                     (__attribute__((address_space(3))) void*)(lp), 16, 0, 0)

// ---------------- merged prep: blocks [0,NTOK) = LayerNorm, [NTOK,NTOK+512) = W1 transpose ----------------
__global__ __launch_bounds__(256) void prep_kernel(const float* __restrict__ dec,
                                                   const float* __restrict__ lng,
                                                   const float* __restrict__ lnb,
                                                   const float* __restrict__ W2,
                                                   const float* __restrict__ b2,
                                                   const float* __restrict__ W3,
                                                   const float* __restrict__ W1,
                                                   _Float16* __restrict__ Af,
                                                   _Float16* __restrict__ W1T,
                                                   _Float16* __restrict__ W2f,
                                                   float* __restrict__ b2f,
                                                   float* __restrict__ w3f) {
    int tid = threadIdx.x;
    if (blockIdx.x < NTOK) {
        // ---- LayerNorm -> f16 A (block 0 also packs MLP frags) ----
        int t = blockIdx.x;
        const float2* row = reinterpret_cast<const float2*>(dec + (size_t)t * DINP);
        float2 v = row[tid];

        __shared__ float red[4];
        __shared__ float stat[2];

        float s = v.x + v.y;
        #pragma unroll
        for (int o = 32; o > 0; o >>= 1) s += __shfl_down(s, o);
        if ((tid & 63) == 0) red[tid >> 6] = s;
        __syncthreads();
        if (tid == 0) stat[0] = (red[0] + red[1] + red[2] + red[3]) * (1.0f / DINP);
        __syncthreads();
        float mu = stat[0];

        float dx = v.x - mu, dy = v.y - mu;
        float q = dx * dx + dy * dy;
        #pragma unroll
        for (int o = 32; o > 0; o >>= 1) q += __shfl_down(q, o);
        if ((tid & 63) == 0) red[tid >> 6] = q;
        __syncthreads();
        if (tid == 0) {
            float var = (red[0] + red[1] + red[2] + red[3]) * (1.0f / DINP);
            stat[1] = 1.0f / sqrtf(var + 1e-5f);
        }
        __syncthreads();
        float rstd = stat[1];

        int c = 2 * tid;
        h2 o2;
        o2.x = (_Float16)(dx * rstd * lng[c]     + lnb[c]);
        o2.y = (_Float16)(dy * rstd * lng[c + 1] + lnb[c + 1]);
        *reinterpret_cast<h2*>(Af + (size_t)t * DINP + c) = o2;

        // block 0: pack MLP weights into MFMA fragment order.
        if (blockIdx.x == 0 && tid < 128) {
            int jt = tid >> 6, l = tid & 63;
            int sub = l & 15, g = l >> 4;
            #pragma unroll
            for (int e = 0; e < 4; ++e) {
                W2f[(jt * 64 + l) * 4 + e] = (_Float16)W2[(g * 4 + e) * MLPH + jt * 16 + sub];
                b2f[(jt * 64 + l) * 4 + e] = b2[jt * 16 + g * 4 + e];
                w3f[(jt * 64 + l) * 4 + e] = W3[jt * 16 + g * 4 + e];
            }
        }
    } else {
        // ---- W1 (512x4096 f32) -> W1T (4096x512 f16) ----
        __shared__ float st[64][65];
        int blk = blockIdx.x - NTOK;          // [0, 512)
        int c0 = (blk & 63) * 64;
        int k0 = (blk >> 6) * 64;
        {
            int r = tid >> 2, cq = (tid & 3) * 16;
            const float* src = W1 + (size_t)(k0 + r) * ODIM + c0 + cq;
            #pragma unroll
            for (int qq = 0; qq < 4; ++qq) {
                float4 v = *reinterpret_cast<const float4*>(src + qq * 4);
                st[r][cq + qq * 4 + 0] = v.x;
                st[r][cq + qq * 4 + 1] = v.y;
                st[r][cq + qq * 4 + 2] = v.z;
                st[r][cq + qq * 4 + 3] = v.w;
            }
        }
        __syncthreads();
        {
            int cc = tid >> 2, kq = (tid & 3) * 16;
            _Float16 tmp[16];
            #pragma unroll
            for (int i = 0; i < 16; ++i) tmp[i] = (_Float16)st[kq + i][cc];
            _Float16* dst = W1T + (size_t)(c0 + cc) * DINP + k0 + kq;
            *reinterpret_cast<half8*>(dst)     = *reinterpret_cast<half8*>(&tmp[0]);
            *reinterpret_cast<half8*>(dst + 8) = *reinterpret_cast<half8*>(&tmp[8]);
        }
    }
}

// ---------------- MFMA GEMM -> grid_h (B,Z,H,W,F) f16 ----------------
// Round-2 proven 1-phase loop (16 KB LDS -> 8 blocks/CU; the 2-phase dbuf at
// 32 KB dropped occupancy to 5 and was net-neutral, round-7). Added: bijective
// XCD-aware block swizzle (nwg=512, %8==0) — each XCD gets 64 contiguous wgids
// = 2 complete A-panel rows, so the A-panel is reused x32 inside one L2 and
// each XCD's B working set is ~4 MB (= L2). Pure block remap, outputs identical.
__global__ __launch_bounds__(256, 2) void gemm_mfma_kernel(
        const _Float16* __restrict__ Af, const _Float16* __restrict__ W1T,
        const float* __restrict__ bias, _Float16* __restrict__ gh) {
    __shared__ _Float16 As[128 * 32];
    __shared__ _Float16 Bs[128 * 32];

    int tid = threadIdx.x;
    int l = tid & 63, w = tid >> 6;
    int wr = w >> 1, wc = w & 1;

    // XCD swizzle: lin -> (xcd = lin%8 owns chunk of 64) -> new (bx,by)
    int lin = blockIdx.y * gridDim.x + blockIdx.x;   // [0, 512)
    int nl  = (lin & 7) * 64 + (lin >> 3);           // bijective (512 % 8 == 0)
    int bx  = nl & 31, by = nl >> 5;
    int row0 = by * 128;
    int col0 = bx * 128;

    const char* Ag0 = (const char*)Af + (size_t)(row0 + w * 32 + (l >> 2)) * (DINP * 2) + (l & 3) * 16;
    const char* Ag1 = Ag0 + 16 * (DINP * 2);
    const char* Bg0 = (const char*)W1T + (size_t)(col0 + w * 32 + (l >> 2)) * (DINP * 2) + (l & 3) * 16;
    const char* Bg1 = Bg0 + 16 * (DINP * 2);
    char* lA0 = (char*)As + w * 2048;
    char* lA1 = lA0 + 1024;
    char* lB0 = (char*)Bs + w * 2048;
    char* lB1 = lB0 + 1024;

    f32x4 acc[4][4] = {};

    for (int kk = 0; kk < DINP; kk += 32) {
        GLDS16(Ag0, lA0); GLDS16(Ag1, lA1);
        GLDS16(Bg0, lB0); GLDS16(Bg1, lB1);
        Ag0 += 64; Ag1 += 64; Bg0 += 64; Bg1 += 64;
        __syncthreads();

        half8 af[4], bf[4];
        #pragma unroll
        for (int m = 0; m < 4; ++m)
            af[m] = *reinterpret_cast<const half8*>(As + (wr * 64 + m * 16 + (l & 15)) * 32 + (l >> 4) * 8);
        #pragma unroll
        for (int n = 0; n < 4; ++n)
            bf[n] = *reinterpret_cast<const half8*>(Bs + (wc * 64 + n * 16 + (l & 15)) * 32 + (l >> 4) * 8);
        #pragma unroll
        for (int m = 0; m < 4; ++m)
            #pragma unroll
            for (int n = 0; n < 4; ++n)
                acc[m][n] = __builtin_amdgcn_mfma_f32_16x16x32_f16(af[m], bf[n], acc[m][n], 0, 0, 0);
        __syncthreads();
    }

    #pragma unroll
    for (int n = 0; n < 4; ++n) {
        int c = col0 + wc * 64 + n * 16 + (l & 15);
        float bv = bias[c];
        int f = c & 15, z = (c >> 4) & 15, v = (c >> 8) & 3, u = (c >> 10) & 3;
        #pragma unroll
        for (int m = 0; m < 4; ++m) {
            int rbase = row0 + wr * 64 + m * 16 + ((l >> 4) << 2);
            #pragma unroll
            for (int j = 0; j < 4; ++j) {
                int t = rbase + j;
                int bb = t >> 10;
                int g = t & 1023;
                int i = g >> 5, j2 = g & 31;
                int h = i * 4 + u, wq = j2 * 4 + v;
                size_t gaddr = ((((size_t)(bb * ZB + z) * HH + h) * WWID + wq) << 4) + f;
                gh[gaddr] = (_Float16)(acc[m][n][j] + bv);
            }
        }
    }
}

// ---------------- transpose grid_h (B,Z,H,W,F) f16 -> nfg (B,F,Z,H,W) f32 ----------------
// Standalone: LDS transpose keeps the 33.5 MB f32 write coalesced (fusing into
// the gemm epilogue scattered dwords -> 149 MB write traffic, round-6 fail).
__global__ __launch_bounds__(256) void tp_kernel(const _Float16* __restrict__ gh,
                                                 float* __restrict__ nfg) {
    int blk = blockIdx.x;           // b*2048 + z*128 + h
    int bb = blk >> 11, z = (blk >> 7) & 15, h = blk & 127;
    __shared__ float sl[128 * 17];  // [w][f] padded
    int tid = threadIdx.x;
    const uint4* src = reinterpret_cast<const uint4*>(gh + (size_t)blk * 2048);
    uint4 v = src[tid];             // 8 f16; idx = tid*8
    int wv = tid >> 1, fb = (tid & 1) * 8;
    h2 p0 = __builtin_bit_cast(h2, v.x);
    h2 p1 = __builtin_bit_cast(h2, v.y);
    h2 p2 = __builtin_bit_cast(h2, v.z);
    h2 p3 = __builtin_bit_cast(h2, v.w);
    float* sr = &sl[wv * 17 + fb];
    sr[0] = (float)p0.x; sr[1] = (float)p0.y;
    sr[2] = (float)p1.x; sr[3] = (float)p1.y;
    sr[4] = (float)p2.x; sr[5] = (float)p2.y;
    sr[6] = (float)p3.x; sr[7] = (float)p3.y;
    __syncthreads();
    int f = tid >> 4, w0 = (tid & 15) * 8;
    float* dst = nfg + (((size_t)(bb * FD + f) * ZB + z) * (HH * WWID)) + h * WWID + w0;
    float4 o0, o1;
    o0.x = sl[(w0 + 0) * 17 + f]; o0.y = sl[(w0 + 1) * 17 + f];
    o0.z = sl[(w0 + 2) * 17 + f]; o0.w = sl[(w0 + 3) * 17 + f];
    o1.x = sl[(w0 + 4) * 17 + f]; o1.y = sl[(w0 + 5) * 17 + f];
    o1.z = sl[(w0 + 6) * 17 + f]; o1.w = sl[(w0 + 7) * 17 + f];
    *reinterpret_cast<float4*>(dst) = o0;
    *reinterpret_cast<float4*>(dst + 4) = o1;
}

// ---------------- gather helper: trilinear via 4x 64B pair-loads (w-corners contiguous) ----------------
// (round-2 proven version, bit-identical accumulation; 16 x 16B requests/sample
// = the minimum for the 256B of corner data -> request-count floor)
__device__ __forceinline__ void gather_feat(const _Float16* __restrict__ gb,
                                            float px, float py, float pz,
                                            h2* __restrict__ a) {
    float fw = (py * (1.0f / 51.2f) + 1.0f) * 63.5f;
    float fh = (px * (1.0f / 51.2f) + 1.0f) * 63.5f;
    float fd = (pz + 5.0f) * (0.25f * 7.5f);
    float w0f = floorf(fw), h0f = floorf(fh), d0f = floorf(fd);
    float tw = fw - w0f, th = fh - h0f, td = fd - d0f;
    int w0 = (int)w0f, h0 = (int)h0f, d0 = (int)d0f;

    float aw0 = (w0 >= 0 && w0 <= WWID - 1) ? (1.0f - tw) : 0.0f;
    float aw1 = (w0 + 1 >= 0 && w0 + 1 <= WWID - 1) ? tw : 0.0f;
    float ah0 = (h0 >= 0 && h0 <= HH - 1) ? (1.0f - th) : 0.0f;
    float ah1 = (h0 + 1 >= 0 && h0 + 1 <= HH - 1) ? th : 0.0f;
    float ad0 = (d0 >= 0 && d0 <= ZB - 1) ? (1.0f - td) : 0.0f;
    float ad1 = (d0 + 1 >= 0 && d0 + 1 <= ZB - 1) ? td : 0.0f;

    // all-corner-weights-zero -> output is exactly zero; skip every load.
    if ((ad0 + ad1) * (ah0 + ah1) * (aw0 + aw1) <= 0.0f) return;

    int h0c = min(max(h0, 0), HH - 1),   h1c = min(max(h0 + 1, 0), HH - 1);
    int d0c = min(max(d0, 0), ZB - 1),   d1c = min(max(d0 + 1, 0), ZB - 1);
    // w pair: both slots always valid memory; weights route aw0/aw1 to the right slot.
    int wb = min(max(w0, 0), WWID - 2);
    float ws0 = (wb == w0) ? aw0 : ((wb == w0 + 1) ? aw1 : 0.0f);
    float ws1 = (wb == w0) ? aw1 : ((wb == w0 - 1) ? aw0 : 0.0f);

    int od0 = d0c * (HH * WWID * FD), od1 = d1c * (HH * WWID * FD);
    int oh0 = h0c * (WWID * FD),      oh1 = h1c * (WWID * FD);
    int ow  = wb * FD;

#define CPAIR(OFF, WDH) do { \
        const uint4* cp_ = reinterpret_cast<const uint4*>(gb + (OFF)); \
        uint4 A_ = cp_[0], B_ = cp_[1], C_ = cp_[2], D_ = cp_[3]; \
        _Float16 u0_ = (_Float16)((WDH) * ws0); \
        _Float16 u1_ = (_Float16)((WDH) * ws1); \
        h2 W0_ = {u0_, u0_}; h2 W1_ = {u1_, u1_}; \
        a[0] += __builtin_bit_cast(h2, A_.x) * W0_; \
        a[1] += __builtin_bit_cast(h2, A_.y) * W0_; \
        a[2] += __builtin_bit_cast(h2, A_.z) * W0_; \
        a[3] += __builtin_bit_cast(h2, A_.w) * W0_; \
        a[4] += __builtin_bit_cast(h2, B_.x) * W0_; \
        a[5] += __builtin_bit_cast(h2, B_.y) * W0_; \
        a[6] += __builtin_bit_cast(h2, B_.z) * W0_; \
        a[7] += __builtin_bit_cast(h2, B_.w) * W0_; \
        a[0] += __builtin_bit_cast(h2, C_.x) * W1_; \
        a[1] += __builtin_bit_cast(h2, C_.y) * W1_; \
        a[2] += __builtin_bit_cast(h2, C_.z) * W1_; \
        a[3] += __builtin_bit_cast(h2, C_.w) * W1_; \
        a[4] += __builtin_bit_cast(h2, D_.x) * W1_; \
        a[5] += __builtin_bit_cast(h2, D_.y) * W1_; \
        a[6] += __builtin_bit_cast(h2, D_.z) * W1_; \
        a[7] += __builtin_bit_cast(h2, D_.w) * W1_; \
    } while (0)

    CPAIR(od0 + oh0 + ow, ad0 * ah0);
    CPAIR(od0 + oh1 + ow, ad0 * ah1);
    CPAIR(od1 + oh0 + ow, ad1 * ah0);
    CPAIR(od1 + oh1 + ow, ad1 * ah1);
#undef CPAIR
}

// ---------------- fused ray kernel: ONE WAVE PER RAY (round-2 proven local optimum) ----------------
// 12 KB/block, time-shared 64-row LDS buffer between the two sample sets.
// 3 structural rewrites (chunk-across-lanes, 2-wave split, tp-merge) all lost;
// this structure sits at the scattered-request floor.
#define SF 24   // feat LDS stride (halves): 48B rows -> 16B aligned, 2-way banks max
__global__ __launch_bounds__(256) void ray_fused_kernel(
        const float* __restrict__ orig, const float* __restrict__ dirs,
        const _Float16* __restrict__ gh,
        const _Float16* __restrict__ W2f, const float* __restrict__ b2f,
        const float* __restrict__ w3f, const float* __restrict__ b3,
        float* __restrict__ pred_out, float* __restrict__ w_out) {
    int tid = threadIdx.x;
    int lane = tid & 63, wvid = tid >> 6;
    int ray = blockIdx.x * 4 + wvid;
    int bb = ray >> 13;

    __shared__ _Float16 featLDS[4 * 64 * SF];   // 12KB
    _Float16* FL = &featLDS[wvid * 64 * SF];

    const float* o3 = orig + (size_t)ray * 3;
    const float* d3 = dirs + (size_t)ray * 3;
    float ox = o3[0], oy = o3[1], oz = o3[2];
    float dx = d3[0], dy = d3[1], dz = d3[2];

    const _Float16* gb = gh + (size_t)bb * (ZB * HH * WWID * FD);

    float t0 = 1.0f + 49.0f * ((float)lane * (1.0f / 127.0f));
    float t1 = 1.0f + 49.0f * ((float)(lane + 64) * (1.0f / 127.0f));

    h2 acc0[8] = {}, acc1[8] = {};
    gather_feat(gb, ox + dx * t0, oy + dy * t0, oz + dz * t0, acc0);
    gather_feat(gb, ox + dx * t1, oy + dy * t1, oz + dz * t1, acc1);

    half4 Af0 = *reinterpret_cast<const half4*>(W2f + lane * 4);
    half4 Af1 = *reinterpret_cast<const half4*>(W2f + (64 + lane) * 4);
    f32x4 b20 = *reinterpret_cast<const f32x4*>(b2f + lane * 4);
    f32x4 b21 = *reinterpret_cast<const f32x4*>(b2f + (64 + lane) * 4);
    f32x4 w30 = *reinterpret_cast<const f32x4*>(w3f + lane * 4);
    f32x4 w31 = *reinterpret_cast<const f32x4*>(w3f + (64 + lane) * 4);
    float b3v = b3[0];

    float at[8];

    // ---- pass A: samples 0..63 (acc0) ----
    {
        uint4 p0, p1;
        p0.x = __builtin_bit_cast(unsigned int, acc0[0]);
        p0.y = __builtin_bit_cast(unsigned int, acc0[1]);
        p0.z = __builtin_bit_cast(unsigned int, acc0[2]);
        p0.w = __builtin_bit_cast(unsigned int, acc0[3]);
        p1.x = __builtin_bit_cast(unsigned int, acc0[4]);
        p1.y = __builtin_bit_cast(unsigned int, acc0[5]);
        p1.z = __builtin_bit_cast(unsigned int, acc0[6]);
        p1.w = __builtin_bit_cast(unsigned int, acc0[7]);
        *reinterpret_cast<uint4*>(FL + lane * SF)     = p0;
        *reinterpret_cast<uint4*>(FL + lane * SF + 8) = p1;
        // same-wave ds_write -> ds_read: compiler inserts lgkmcnt wait; no barrier needed
        #pragma unroll
        for (int tt = 0; tt < 4; ++tt) {
            half4 bfrag = *reinterpret_cast<const half4*>(
                FL + (tt * 16 + (lane & 15)) * SF + (lane >> 4) * 4);
            f32x4 c0 = __builtin_amdgcn_mfma_f32_16x16x16f16(Af0, bfrag, b20, 0, 0, 0);
            f32x4 c1 = __builtin_amdgcn_mfma_f32_16x16x16f16(Af1, bfrag, b21, 0, 0, 0);
            float p = 0.0f;
            #pragma unroll
            for (int r = 0; r < 4; ++r) {
                p = fmaf(fmaxf(c0[r], 0.0f), w30[r], p);
                p = fmaf(fmaxf(c1[r], 0.0f), w31[r], p);
            }
            p += __shfl_xor(p, 16);
            p += __shfl_xor(p, 32);
            at[tt] = p;
        }
    }
    // ---- pass B: samples 64..127 (acc1), same LDS rows (WAR ordered within wave) ----
    {
        uint4 q0, q1;
        q0.x = __builtin_bit_cast(unsigned int, acc1[0]);
        q0.y = __builtin_bit_cast(unsigned int, acc1[1]);
        q0.z = __builtin_bit_cast(unsigned int, acc1[2]);
        q0.w = __builtin_bit_cast(unsigned int, acc1[3]);
        q1.x = __builtin_bit_cast(unsigned int, acc1[4]);
        q1.y = __builtin_bit_cast(unsigned int, acc1[5]);
        q1.z = __builtin_bit_cast(unsigned int, acc1[6]);
        q1.w = __builtin_bit_cast(unsigned int, acc1[7]);
        *reinterpret_cast<uint4*>(FL + lane * SF)     = q0;
        *reinterpret_cast<uint4*>(FL + lane * SF + 8) = q1;
        #pragma unroll
        for (int tt = 0; tt < 4; ++tt) {
            half4 bfrag = *reinterpret_cast<const half4*>(
                FL + (tt * 16 + (lane & 15)) * SF + (lane >> 4) * 4);
            f32x4 c0 = __builtin_amdgcn_mfma_f32_16x16x16f16(Af0, bfrag, b20, 0, 0, 0);
            f32x4 c1 = __builtin_amdgcn_mfma_f32_16x16x16f16(Af1, bfrag, b21, 0, 0, 0);
            float p = 0.0f;
            #pragma unroll
            for (int r = 0; r < 4; ++r) {
                p = fmaf(fmaxf(c0[r], 0.0f), w30[r], p);
                p = fmaf(fmaxf(c1[r], 0.0f), w31[r], p);
            }
            p += __shfl_xor(p, 16);
            p += __shfl_xor(p, 32);
            at[tt + 4] = p;
        }
    }

    int g2 = lane >> 4;
    float aS0 = at[0];
    aS0 = (g2 == 1) ? at[1] : aS0;
    aS0 = (g2 == 2) ? at[2] : aS0;
    aS0 = (g2 == 3) ? at[3] : aS0;
    float aS1 = at[4];
    aS1 = (g2 == 1) ? at[5] : aS1;
    aS1 = (g2 == 2) ? at[6] : aS1;
    aS1 = (g2 == 3) ? at[7] : aS1;
    aS0 += b3v; aS1 += b3v;

    float alpha0 = 1.0f / (1.0f + __expf(-aS0));
    float alpha1 = 1.0f / (1.0f + __expf(-aS1));
    float oma0 = 1.0f - alpha0 + 1e-10f;
    float oma1 = 1.0f - alpha1 + 1e-10f;

    // inclusive product scan over first 64 samples
    float P = oma0;
    #pragma unroll
    for (int off = 1; off < 64; off <<= 1) {
        float u = __shfl_up(P, off);
        if (lane >= off) P *= u;
    }
    float T64 = __shfl(P, 63);      // product of samples 0..63
    // inclusive product scan over second 64 samples
    float Q = oma1;
    #pragma unroll
    for (int off = 1; off < 64; off <<= 1) {
        float u = __shfl_up(Q, off);
        if (lane >= off) Q *= u;
    }
    float e0 = __shfl_up(P, 1);
    if (lane == 0) e0 = 1.0f;
    float e1 = __shfl_up(Q, 1);
    e1 = (lane == 0) ? T64 : e1 * T64;

    float w0 = alpha0 * e0;
    float w1 = alpha1 * e1;
    w_out[(size_t)ray * SNUM + lane] = w0;
    w_out[(size_t)ray * SNUM + 64 + lane] = w1;

    float pv = w0 * t0 + w1 * t1;
    #pragma unroll
    for (int o = 32; o > 0; o >>= 1) pv += __shfl_xor(pv, o);
    if (lane == 0) pred_out[ray] = pv;
}

extern "C" void kernel_launch(void* const* d_in, const int* in_sizes, int n_in,
                              void* d_out, int out_size, void* d_ws, size_t ws_size,
                              hipStream_t stream) {
    const float* dec = (const float*)d_in[0];
    const float* ro  = (const float*)d_in[1];
    const float* rd  = (const float*)d_in[2];
    const float* lng = (const float*)d_in[3];
    const float* lnb = (const float*)d_in[4];
    const float* W1  = (const float*)d_in[5];
    const float* b1  = (const float*)d_in[6];
    const float* W2  = (const float*)d_in[7];
    const float* b2  = (const float*)d_in[8];
    const float* W3  = (const float*)d_in[9];
    const float* b3  = (const float*)d_in[10];

    float* out = (float*)d_out;
    char*  wsb = (char*)d_ws;
    _Float16* Af  = (_Float16*)wsb;                      // 2 MB
    _Float16* W1T = (_Float16*)(wsb + (2u << 20));       // 4 MB
    _Float16* gh  = (_Float16*)(wsb + (6u << 20));       // 16.8 MB
    _Float16* W2f = (_Float16*)(wsb + (23u << 20));              // 1 KB
    float*    b2f = (float*)(wsb + (23u << 20) + 4096);          // 2 KB
    float*    w3f = (float*)(wsb + (23u << 20) + 8192);          // 2 KB

    // dispatch 1: LN (blocks 0..2047) + W1 transpose (blocks 2048..2559)
    prep_kernel<<<NTOK + (ODIM / 64) * (DINP / 64), 256, 0, stream>>>(
        dec, lng, lnb, W2, b2, W3, W1, Af, W1T, W2f, b2f, w3f);

    // dispatch 2: GEMM (1-phase, 8 blocks/CU) + XCD-aware block swizzle
    dim3 gg(ODIM / 128, NTOK / 128);
    gemm_mfma_kernel<<<gg, 256, 0, stream>>>(Af, W1T, b1, gh);

    // dispatch 3: ray march (round-2 proven structure)
    ray_fused_kernel<<<BATCH * RAYS / 4, 256, 0, stream>>>(ro, rd, gh, W2f, b2f, w3f, b3,
                                                           out + OUT_PRED_OFF, out + OUT_W_OFF);

    // dispatch 4: nfg transpose (standalone, coalesced writes)
    tp_kernel<<<BATCH * ZB * HH, 256, 0, stream>>>(gh, out + OUT_NFG_OFF);
}